// Round 8
// baseline (534.217 us; speedup 1.0000x reference)
//
#include <hip/hip_runtime.h>
#include <hip/hip_bf16.h>

typedef __hip_bfloat16 bf16;
typedef __attribute__((ext_vector_type(8))) __bf16 bf16x8;
typedef __attribute__((ext_vector_type(4))) float f32x4;

static constexpr int N = 100000;
static constexpr int E = 1600000;
static constexpr int ETOT = E + N;   // self-loops appended after the E edges
static constexpr float SLOPE = 0.2f;

// ---- param table: W1,as1,ad1,b1, W2,as2,ad2,b2, W3,as3,ad3,b3 (fp32 flat) --
__device__ __constant__ int c_poff[12] = {0, 16384, 16512, 16640,
                                          16768, 24960, 25024, 25088,
                                          25152, 26176, 26192, 26208};
static constexpr int PTOT = 26224;
static constexpr int H_POFF[12] = {0, 16384, 16512, 16640, 16768, 24960,
                                   25024, 25088, 25152, 26176, 26192, 26208};

struct Src12 { const void* p[12]; };

__device__ __forceinline__ float bfLo(unsigned u) { return __uint_as_float(u << 16); }
__device__ __forceinline__ float bfHi(unsigned u) { return __uint_as_float(u & 0xFFFF0000u); }

__device__ __forceinline__ void fma8(const uint4 r, float e, float* acc) {
  acc[0] = fmaf(e, bfLo(r.x), acc[0]);
  acc[1] = fmaf(e, bfHi(r.x), acc[1]);
  acc[2] = fmaf(e, bfLo(r.y), acc[2]);
  acc[3] = fmaf(e, bfHi(r.y), acc[3]);
  acc[4] = fmaf(e, bfLo(r.z), acc[4]);
  acc[5] = fmaf(e, bfHi(r.z), acc[5]);
  acc[6] = fmaf(e, bfLo(r.w), acc[6]);
  acc[7] = fmaf(e, bfHi(r.w), acc[7]);
}

__device__ __forceinline__ void fma4(const uint2 r, float e, float* acc) {
  acc[0] = fmaf(e, bfLo(r.x), acc[0]);
  acc[1] = fmaf(e, bfHi(r.x), acc[1]);
  acc[2] = fmaf(e, bfLo(r.y), acc[2]);
  acc[3] = fmaf(e, bfHi(r.y), acc[3]);
}

__device__ __forceinline__ float edge_ex(float l) {
  l = (l > 0.f) ? l : SLOPE * l;
  return __expf(l);
}

__device__ __forceinline__ void loadEdge(const int* __restrict__ ei32,
                                         const long long* __restrict__ ei64,
                                         int use64, int t, int& s, int& d) {
  if (t >= E) { s = d = t - E; return; }
  if (use64) { s = (int)ei64[t]; d = (int)ei64[E + t]; }
  else       { s = ei32[t];      d = ei32[E + t]; }
}

__device__ __forceinline__ unsigned pk2(float a, float b) {
  bf16 x = __float2bfloat16(a), y = __float2bfloat16(b);
  unsigned short ux = *(unsigned short*)&x, uy = *(unsigned short*)&y;
  return ((unsigned)uy << 16) | ux;
}

// ---- bucket-sort geometry ----
static constexpr int CHUNK = 8192;
static constexpr int NCHK  = (ETOT + CHUNK - 1) / CHUNK;   // 208
static constexpr int NB1   = (N + 511) / 512;              // 196 coarse buckets
static constexpr int M1    = NB1 * NCHK;                   // 40768
static constexpr int SBLK  = (M1 + 255) / 256;             // 160

// ---- flags: flags[0]=edge idx is int64; flags[1]=float tensors are fp32 ---
__global__ __launch_bounds__(256) void detect_kernel(
    const unsigned long long* __restrict__ ei64,
    const unsigned short* __restrict__ w1u16, int* __restrict__ flags) {
  const int t = threadIdx.x;
  __shared__ unsigned long long bl[4];
  __shared__ unsigned long long sb64;
  const int w = t >> 6;
  bool p64 = (t < 64) && (ei64[t] >= (unsigned long long)N);
  unsigned long long b64 = __ballot(p64);
  if (t == 0) sb64 = b64;
  // W1 glorot-bounded (|v|<=0.154) -> bf16 exp field < 126; fp32 low halves
  // are random -> exp>=126 appears within 256 samples w.h.p.
  bool pf = (((w1u16[t] >> 7) & 0xFFu) >= 126u);
  unsigned long long bf_ = __ballot(pf);
  if ((t & 63) == 0) bl[w] = bf_;
  __syncthreads();
  if (t == 0) {
    flags[0] = (sb64 == 0ull) ? 1 : 0;
    flags[1] = ((bl[0] | bl[1] | bl[2] | bl[3]) != 0ull) ? 1 : 0;
  }
}

// ---- K2: phase A (coarse LDS histogram) || param/W converts ---------------
static constexpr int PB_PAR = (PTOT + 255) / 256;  // 103
static constexpr int PB_W1  = 128 * 128 / 256;     // 64
static constexpr int PB_W2  = 128 * 64 / 256;      // 32
static constexpr int PB_W3  = 64 * 16 / 256;       // 4
static constexpr int PB_TOT = NCHK + PB_PAR + PB_W1 + PB_W2 + PB_W3;

__device__ __forceinline__ void conv_w(const void* W, int kd, int dout, int f32,
                                       bf16* __restrict__ wt, int idx) {
  int n = idx / kd, k = idx - n * kd;
  float v = f32 ? ((const float*)W)[k * dout + n]
                : __bfloat162float(((const bf16*)W)[k * dout + n]);
  wt[idx] = __float2bfloat16(v);
}

__global__ __launch_bounds__(256) void prep_kernel(
    const int* __restrict__ ei32, const long long* __restrict__ ei64,
    const int* __restrict__ flags, int* __restrict__ c1,
    Src12 s, float* __restrict__ prm,
    bf16* __restrict__ w1t, bf16* __restrict__ w2t, bf16* __restrict__ w3t) {
  const int b = blockIdx.x, tid = threadIdx.x;
  const int f64 = flags[0], f32 = flags[1];
  if (b < NCHK) {
    __shared__ int h1[NB1];
    if (tid < NB1) h1[tid] = 0;
    __syncthreads();
    const int t0 = b * CHUNK;
#pragma unroll 4
    for (int i = tid; i < CHUNK; i += 256) {
      int t = t0 + i;
      if (t < ETOT) {
        int d = (t >= E) ? (t - E) : (f64 ? (int)ei64[E + t] : ei32[E + t]);
        atomicAdd(&h1[d >> 9], 1);
      }
    }
    __syncthreads();
    if (tid < NB1) c1[tid * NCHK + b] = h1[tid];   // bin-major
  } else if (b < NCHK + PB_PAR) {
    int t = (b - NCHK) * 256 + tid;
    if (t < PTOT) {
      int k = 0;
#pragma unroll
      for (int i = 1; i < 12; ++i)
        if (t >= c_poff[i]) k = i;
      int j = t - c_poff[k];
      prm[t] = f32 ? ((const float*)s.p[k])[j]
                   : __bfloat162float(((const bf16*)s.p[k])[j]);
    }
  } else if (b < NCHK + PB_PAR + PB_W1) {
    conv_w(s.p[0], 128, 128, f32, w1t, (b - NCHK - PB_PAR) * 256 + tid);
  } else if (b < NCHK + PB_PAR + PB_W1 + PB_W2) {
    conv_w(s.p[4], 128, 64, f32, w2t, (b - NCHK - PB_PAR - PB_W1) * 256 + tid);
  } else {
    conv_w(s.p[8], 64, 16, f32, w3t, (b - NCHK - PB_PAR - PB_W1 - PB_W2) * 256 + tid);
  }
}

// ---- 3-phase exclusive scan of c1[0..M1) -> off1 --------------------------
__global__ __launch_bounds__(256) void scanA_kernel(const int* __restrict__ c1,
                                                    int* __restrict__ bsum) {
  __shared__ int red[256];
  const int t = threadIdx.x;
  const int i = blockIdx.x * 256 + t;
  red[t] = (i < M1) ? c1[i] : 0;
  __syncthreads();
#pragma unroll
  for (int off = 128; off > 0; off >>= 1) {
    if (t < off) red[t] += red[t + off];
    __syncthreads();
  }
  if (t == 0) bsum[blockIdx.x] = red[0];
}

__global__ __launch_bounds__(256) void scanB_kernel(const int* __restrict__ bsum,
                                                    int* __restrict__ boff) {
  __shared__ int s[256];
  const int t = threadIdx.x;
  const int v = (t < SBLK) ? bsum[t] : 0;
  s[t] = v;
  __syncthreads();
  for (int off = 1; off < 256; off <<= 1) {
    int u = (t >= off) ? s[t - off] : 0;
    __syncthreads();
    s[t] += u;
    __syncthreads();
  }
  if (t < SBLK) boff[t] = s[t] - v;
}

__global__ __launch_bounds__(256) void scanC_kernel(const int* __restrict__ c1,
                                                    const int* __restrict__ boff,
                                                    int* __restrict__ off1) {
  __shared__ int s[256];
  const int t = threadIdx.x;
  const int i = blockIdx.x * 256 + t;
  const int v = (i < M1) ? c1[i] : 0;
  s[t] = v;
  __syncthreads();
#pragma unroll
  for (int off = 1; off < 256; off <<= 1) {
    int u = (t >= off) ? s[t - off] : 0;
    __syncthreads();
    s[t] += u;
    __syncthreads();
  }
  if (i < M1) off1[i] = boff[blockIdx.x] + s[t] - v;
}

// ---- phase C body: scatter edges into coarse buckets via LDS cursors ------
__device__ __forceinline__ void phaseC_body(int c, const int* __restrict__ ei32,
                                            const long long* __restrict__ ei64,
                                            int f64, const int* __restrict__ off1,
                                            int2* __restrict__ tmp) {
  __shared__ int cur[NB1];
  const int tid = threadIdx.x;
  if (tid < NB1) cur[tid] = off1[tid * NCHK + c];
  __syncthreads();
  const int t0 = c * CHUNK;
#pragma unroll 4
  for (int i = tid; i < CHUNK; i += 256) {
    int t = t0 + i;
    if (t < ETOT) {
      int s, d;
      loadEdge(ei32, ei64, f64, t, s, d);
      int pos = atomicAdd(&cur[d >> 9], 1);
      tmp[pos] = make_int2(d, s);
    }
  }
}

// ---- phase D: per-bucket fine counting sort -> rowptr + ssrt --------------
__global__ __launch_bounds__(256) void phaseD_kernel(const int* __restrict__ off1,
                                                     const int2* __restrict__ tmp,
                                                     int* __restrict__ rowptr,
                                                     int* __restrict__ ssrt) {
  __shared__ int h2[512], e2[512], cur[512];
  __shared__ int ps[256];
  const int b = blockIdx.x, t = threadIdx.x;
  const int base = off1[b * NCHK];
  const int end = (b + 1 < NB1) ? off1[(b + 1) * NCHK] : ETOT;
  const int len = end - base;
  h2[2 * t] = 0; h2[2 * t + 1] = 0;
  __syncthreads();
  for (int i = t; i < len; i += 256)
    atomicAdd(&h2[tmp[base + i].x & 511], 1);
  __syncthreads();
  // exclusive scan of h2[512] via 256 pair-partials
  const int s1 = h2[2 * t], s2 = h2[2 * t + 1];
  ps[t] = s1 + s2;
  __syncthreads();
  for (int off = 1; off < 256; off <<= 1) {
    int u = (t >= off) ? ps[t - off] : 0;
    __syncthreads();
    ps[t] += u;
    __syncthreads();
  }
  const int ep = ps[t] - (s1 + s2);   // exclusive pair prefix
  e2[2 * t] = ep;
  e2[2 * t + 1] = ep + s1;
  cur[2 * t] = ep;
  cur[2 * t + 1] = ep + s1;
  __syncthreads();
  // rowptr for the 512 dst nodes of this bucket
#pragma unroll
  for (int k = 0; k < 2; ++k) {
    int f = 2 * t + k;
    int node = (b << 9) + f;
    if (node < N) rowptr[node] = base + e2[f];
  }
  if (b == 0 && t == 0) rowptr[N] = ETOT;
  // scatter src into final dst-sorted order
  for (int i = t; i < len; i += 256) {
    int2 e = tmp[base + i];
    int pos = base + atomicAdd(&cur[e.x & 511], 1);
    ssrt[pos] = e.y;
  }
}

// -------- MFMA GEMM body (64 rows x DOUT) + fused al epilogue --------------
// XD: stage A directly from x (fp32 or bf16 per flags[1]).
// ASLAB>0: A input is 16-col-slabbed [ASLAB][N][16] (from agg_slab).
// h output is ALWAYS slabbed [NT][N][16] (slab t), so the next layer's
// agg_slab can keep a per-XCD-resident column slab in L2.
template <int KD, int DOUT, bool XD, int ASLAB>
__device__ __forceinline__ void gemm_body(int bb, const void* __restrict__ inv,
                                          const int* __restrict__ flags,
                                          const unsigned short* __restrict__ wt,
                                          bf16* __restrict__ h,
                                          const float* __restrict__ a_s,
                                          const float* __restrict__ a_d,
                                          float* __restrict__ als,
                                          float* __restrict__ ald) {
  constexpr int SA = KD + 8;
  constexpr int NT = DOUT / 16;      // 8 / 4 / 1
  constexpr int KS = KD / 32;        // 4 / 4 / 2
  __shared__ unsigned short sA[64 * SA];
  __shared__ unsigned short sB[DOUT * SA];
  const int tid = threadIdx.x;
  const int m0 = bb * 64;
  for (int idx = tid; idx < DOUT * KD / 8; idx += 256) {
    int n = idx / (KD / 8), k8 = idx - n * (KD / 8);
    *(uint4*)(sB + n * SA + k8 * 8) = *(const uint4*)(wt + n * KD + k8 * 8);
  }
  const bool f32 = XD ? (flags[1] != 0) : false;
  for (int idx = tid; idx < 64 * KD / 8; idx += 256) {
    int r = idx / (KD / 8), k8 = idx - r * (KD / 8);
    int m = m0 + r;
    uint4 v = make_uint4(0, 0, 0, 0);
    if (m < N) {
      if (XD && f32) {
        const float4 v0 = *((const float4*)inv + ((size_t)m * KD + k8 * 8) / 4);
        const float4 v1 = *((const float4*)inv + ((size_t)m * KD + k8 * 8) / 4 + 1);
        v = make_uint4(pk2(v0.x, v0.y), pk2(v0.z, v0.w),
                       pk2(v1.x, v1.y), pk2(v1.z, v1.w));
      } else if (ASLAB > 0) {
        const unsigned short* inS = (const unsigned short*)inv;
        v = *(const uint4*)(inS + ((size_t)(k8 >> 1) * N + m) * 16 + (k8 & 1) * 8);
      } else {
        v = *((const uint4*)inv + ((size_t)m * KD + k8 * 8) / 8);
      }
    }
    *(uint4*)(sA + r * SA + k8 * 8) = v;
  }
  __syncthreads();
  const int lane = tid & 63;
  const int wv = tid >> 6;
  const int lr = lane & 15;
  const int q = lane >> 4;
  f32x4 acc[NT];
#pragma unroll
  for (int t = 0; t < NT; ++t)
#pragma unroll
    for (int r = 0; r < 4; ++r) acc[t][r] = 0.f;
  const int arow = wv * 16 + lr;
#pragma unroll
  for (int ks = 0; ks < KS; ++ks) {
    const int k0 = ks * 32 + q * 8;
    const bf16x8 a = *(const bf16x8*)(sA + arow * SA + k0);
#pragma unroll
    for (int t = 0; t < NT; ++t) {
      const bf16x8 b = *(const bf16x8*)(sB + (t * 16 + lr) * SA + k0);
      acc[t] = __builtin_amdgcn_mfma_f32_16x16x32_bf16(a, b, acc[t], 0, 0, 0);
    }
  }
  // al epilogue: row-dots with a_s/a_d, reduce over 16 col-lanes
  float ps[4] = {0.f, 0.f, 0.f, 0.f}, pd[4] = {0.f, 0.f, 0.f, 0.f};
#pragma unroll
  for (int t = 0; t < NT; ++t) {
    const float av = a_s[t * 16 + lr];
    const float dv = a_d[t * 16 + lr];
#pragma unroll
    for (int r = 0; r < 4; ++r) {
      ps[r] = fmaf(acc[t][r], av, ps[r]);
      pd[r] = fmaf(acc[t][r], dv, pd[r]);
    }
  }
#pragma unroll
  for (int m = 1; m < 16; m <<= 1)
#pragma unroll
    for (int r = 0; r < 4; ++r) {
      ps[r] += __shfl_xor(ps[r], m, 64);
      pd[r] += __shfl_xor(pd[r], m, 64);
    }
  const int mb = m0 + wv * 16 + q * 4;
  if (lr == 0) {
#pragma unroll
    for (int r = 0; r < 4; ++r) {
      int m = mb + r;
      if (m < N) { als[m] = ps[r]; ald[m] = pd[r]; }
    }
  }
#pragma unroll
  for (int t = 0; t < NT; ++t)
#pragma unroll
    for (int r = 0; r < 4; ++r) {
      int m = mb + r;
      if (m < N) h[((size_t)t * N + m) * 16 + lr] = __float2bfloat16(acc[t][r]);
    }
}

// layer-1 GEMM (direct from x) fused with bucket phase C (independent tasks)
static constexpr int GB1 = (N + 63) / 64;  // 1563

__global__ __launch_bounds__(256) void gemm1_phaseC(
    const void* __restrict__ x, const int* __restrict__ flags,
    const unsigned short* __restrict__ wt, bf16* __restrict__ h,
    const float* __restrict__ a_s, const float* __restrict__ a_d,
    float* __restrict__ als, float* __restrict__ ald,
    const int* __restrict__ ei32, const long long* __restrict__ ei64,
    const int* __restrict__ off1, int2* __restrict__ tmp) {
  if (blockIdx.x < GB1) {
    gemm_body<128, 128, true, 0>(blockIdx.x, x, flags, wt, h, a_s, a_d, als, ald);
  } else {
    int c = blockIdx.x - GB1;
    if (c < NCHK) phaseC_body(c, ei32, ei64, flags[0], off1, tmp);
  }
}

template <int KD, int DOUT, int ASLAB>
__global__ __launch_bounds__(256) void gemm_al(const unsigned short* __restrict__ inb,
                                               const unsigned short* __restrict__ wt,
                                               bf16* __restrict__ h,
                                               const float* __restrict__ a_s,
                                               const float* __restrict__ a_d,
                                               float* __restrict__ als,
                                               float* __restrict__ ald) {
  gemm_body<KD, DOUT, false, ASLAB>(blockIdx.x, inb, nullptr, wt, h, a_s, a_d, als, ald);
}

// ---- column-slab aggregate -----------------------------------------------
// h is stored as NSLAB slabs of 16 cols: [NSLAB][N][16] (3.2 MB/slab).
// slab = blockIdx.x % NSLAB: under the default round-robin wg->XCD dispatch,
// all slab-k blocks land on XCD k (k, k+4 for NSLAB=4) -> the slab is
// L2-RESIDENT per XCD, so the random src-row gather hits L2 (~200cy) instead
// of L3 (~600cy+196MB fill). Round-6 counters: FETCH 195MB ~= 8 XCDs x full
// hbuf = the compulsory floor for row-major; slabbing cuts it to ~1x + edge
// streams. TPN=2 threads/node x 8 cols keeps per-edge visits at 16 (same
// VALU as round-6). Output hAs is slabbed too (full-line per-XCD writes).
template <int NSLAB>
__global__ __launch_bounds__(256) void agg_slab(
    const int* __restrict__ rowptr, const int* __restrict__ ssrt,
    const float* __restrict__ als, const float* __restrict__ ald,
    const unsigned short* __restrict__ hbS, const float* __restrict__ bias,
    unsigned short* __restrict__ hAs) {
  const int slab = blockIdx.x % NSLAB;
  const int d = (blockIdx.x / NSLAB) * 128 + (threadIdx.x >> 1);
  if (d >= N) return;
  const int sub = threadIdx.x & 1;
  const int co = sub * 8;
  const size_t sbase = (size_t)slab * N;
  const unsigned short* hs = hbS + sbase * 16 + co;
  const int p0 = rowptr[d], p1 = rowptr[d + 1];
  const float ad = ald[d];
  float acc[8];
#pragma unroll
  for (int c = 0; c < 8; ++c) acc[c] = 0.f;
  float sum = 0.f;
  int p = p0;
  for (; p + 4 <= p1; p += 4) {
    const int s0 = __builtin_nontemporal_load(ssrt + p + 0);
    const int s1 = __builtin_nontemporal_load(ssrt + p + 1);
    const int s2 = __builtin_nontemporal_load(ssrt + p + 2);
    const int s3 = __builtin_nontemporal_load(ssrt + p + 3);
    const uint4 r0 = *reinterpret_cast<const uint4*>(hs + (size_t)s0 * 16);
    const uint4 r1 = *reinterpret_cast<const uint4*>(hs + (size_t)s1 * 16);
    const uint4 r2 = *reinterpret_cast<const uint4*>(hs + (size_t)s2 * 16);
    const uint4 r3 = *reinterpret_cast<const uint4*>(hs + (size_t)s3 * 16);
    const float x0 = edge_ex(als[s0] + ad);
    const float x1 = edge_ex(als[s1] + ad);
    const float x2 = edge_ex(als[s2] + ad);
    const float x3 = edge_ex(als[s3] + ad);
    sum += (x0 + x1) + (x2 + x3);
    fma8(r0, x0, acc);
    fma8(r1, x1, acc);
    fma8(r2, x2, acc);
    fma8(r3, x3, acc);
  }
  for (; p < p1; ++p) {
    const int s = __builtin_nontemporal_load(ssrt + p);
    const uint4 rr = *reinterpret_cast<const uint4*>(hs + (size_t)s * 16);
    const float x = edge_ex(als[s] + ad);
    sum += x;
    fma8(rr, x, acc);
  }
  const float inv = 1.f / sum;
  float v[8];
#pragma unroll
  for (int c = 0; c < 8; ++c) {
    float t = acc[c] * inv + bias[slab * 16 + co + c];
    v[c] = (t > 0.f) ? t : 0.f;   // ReLU between layers
  }
  const uint4 w = make_uint4(pk2(v[0], v[1]), pk2(v[2], v[3]),
                             pk2(v[4], v[5]), pk2(v[6], v[7]));
  *(uint4*)(hAs + (sbase + d) * 16 + co) = w;
}

// ---- final aggregate (V=4 cols per thread; h3 = [N][16], L2-fits) ---------
template <int DOUT, bool RELU, bool FINAL>
__global__ __launch_bounds__(256) void aggregate_csr(const int* __restrict__ rowptr,
                                                     const int* __restrict__ ssrt,
                                                     const float* __restrict__ als,
                                                     const float* __restrict__ ald,
                                                     const unsigned short* __restrict__ hb,
                                                     const float* __restrict__ bias,
                                                     bf16* __restrict__ outb,
                                                     void* __restrict__ outv,
                                                     const int* __restrict__ flags) {
  constexpr int V = (DOUT >= 64) ? 8 : 4;
  constexpr int TPN = DOUT / V;
  constexpr int NPB = 256 / TPN;
  const int sub = threadIdx.x % TPN;
  const int d = blockIdx.x * NPB + threadIdx.x / TPN;
  if (d >= N) return;
  const int p0 = rowptr[d], p1 = rowptr[d + 1];
  const float ad = ald[d];
  const int col0 = sub * V;
  float acc[V];
#pragma unroll
  for (int c = 0; c < V; ++c) acc[c] = 0.f;
  float sum = 0.f;
  int p = p0;
  for (; p + 4 <= p1; p += 4) {
    const int s0 = ssrt[p + 0];
    const int s1 = ssrt[p + 1];
    const int s2 = ssrt[p + 2];
    const int s3 = ssrt[p + 3];
    const float x0 = edge_ex(als[s0] + ad);
    const float x1 = edge_ex(als[s1] + ad);
    const float x2 = edge_ex(als[s2] + ad);
    const float x3 = edge_ex(als[s3] + ad);
    sum += (x0 + x1) + (x2 + x3);
    if constexpr (V == 8) {
      const uint4 r0 = *reinterpret_cast<const uint4*>(hb + (size_t)s0 * DOUT + col0);
      const uint4 r1 = *reinterpret_cast<const uint4*>(hb + (size_t)s1 * DOUT + col0);
      const uint4 r2 = *reinterpret_cast<const uint4*>(hb + (size_t)s2 * DOUT + col0);
      const uint4 r3 = *reinterpret_cast<const uint4*>(hb + (size_t)s3 * DOUT + col0);
      fma8(r0, x0, acc);
      fma8(r1, x1, acc);
      fma8(r2, x2, acc);
      fma8(r3, x3, acc);
    } else {
      const uint2 r0 = *reinterpret_cast<const uint2*>(hb + (size_t)s0 * DOUT + col0);
      const uint2 r1 = *reinterpret_cast<const uint2*>(hb + (size_t)s1 * DOUT + col0);
      const uint2 r2 = *reinterpret_cast<const uint2*>(hb + (size_t)s2 * DOUT + col0);
      const uint2 r3 = *reinterpret_cast<const uint2*>(hb + (size_t)s3 * DOUT + col0);
      fma4(r0, x0, acc);
      fma4(r1, x1, acc);
      fma4(r2, x2, acc);
      fma4(r3, x3, acc);
    }
  }
  for (; p < p1; ++p) {
    const int s = ssrt[p];
    const float x = edge_ex(als[s] + ad);
    sum += x;
    if constexpr (V == 8) {
      const uint4 r = *reinterpret_cast<const uint4*>(hb + (size_t)s * DOUT + col0);
      fma8(r, x, acc);
    } else {
      const uint2 r = *reinterpret_cast<const uint2*>(hb + (size_t)s * DOUT + col0);
      fma4(r, x, acc);
    }
  }
  const float inv = 1.f / sum;
  if (FINAL) {
    const bool f32o = flags[1] != 0;
#pragma unroll
    for (int c = 0; c < V; ++c) {
      float v = acc[c] * inv + bias[col0 + c];
      if (f32o) ((float*)outv)[(size_t)d * DOUT + col0 + c] = v;
      else      ((bf16*)outv)[(size_t)d * DOUT + col0 + c] = __float2bfloat16(v);
    }
  } else {
#pragma unroll
    for (int c = 0; c < V; ++c) {
      float v = acc[c] * inv + bias[col0 + c];
      if (RELU) v = (v > 0.f) ? v : 0.f;
      outb[(size_t)d * DOUT + col0 + c] = __float2bfloat16(v);
    }
  }
}

static inline size_t rup(size_t v) { return (v + 255) & ~(size_t)255; }

extern "C" void kernel_launch(void* const* d_in, const int* in_sizes, int n_in,
                              void* d_out, int out_size, void* d_ws, size_t ws_size,
                              hipStream_t stream) {
  const int* ei32 = (const int*)d_in[1];
  const long long* ei64 = (const long long*)d_in[1];

  char* p = (char*)d_ws;
  int*   flags  = (int*)p;   p += 256;
  float* prm    = (float*)p; p += rup((size_t)PTOT * 4);
  bf16*  w1t    = (bf16*)p;  p += rup((size_t)128 * 128 * 2);
  bf16*  w2t    = (bf16*)p;  p += rup((size_t)128 * 64 * 2);
  bf16*  w3t    = (bf16*)p;  p += rup((size_t)64 * 16 * 2);
  float* als1   = (float*)p; p += rup((size_t)N * 4);
  float* ald1   = (float*)p; p += rup((size_t)N * 4);
  float* als2   = (float*)p; p += rup((size_t)N * 4);
  float* ald2   = (float*)p; p += rup((size_t)N * 4);
  int*   rowptr = (int*)p;   p += rup((size_t)(N + 1) * 4);
  int*   c1     = (int*)p;   p += rup((size_t)M1 * 4);
  int*   off1   = (int*)p;   p += rup((size_t)M1 * 4);
  int*   bsum   = (int*)p;   p += rup((size_t)SBLK * 4);
  int*   boff   = (int*)p;   p += rup((size_t)SBLK * 4);
  int2*  tmp    = (int2*)p;  p += rup((size_t)ETOT * 8);   // dead after phaseD
  int*   ssrt   = (int*)p;   p += rup((size_t)ETOT * 4);
  bf16*  h1s    = (bf16*)p;  p += rup((size_t)8 * N * 16 * 2);  // 25.6 MB
  bf16*  hA1s   = (bf16*)p;  p += rup((size_t)8 * N * 16 * 2);  // 25.6 MB
  bf16*  h2s    = (bf16*)p;  p += rup((size_t)4 * N * 16 * 2);  // 12.8 MB
  bf16*  h3     = (bf16*)p;  p += rup((size_t)N * 16 * 2);      // 3.2 MB
  bf16*  hA2s   = (bf16*)tmp;  // alias: tmp (13.6 MB) dead before step 10
  // total ~90 MB (ws proven >= 99 MB)

  Src12 s;
  for (int i = 0; i < 12; ++i) s.p[i] = d_in[2 + i];

  // 1) flags (parallel ballots, 1 block)
  detect_kernel<<<1, 256, 0, stream>>>(
      (const unsigned long long*)d_in[1], (const unsigned short*)d_in[2], flags);
  // 2) coarse LDS histograms || param/W converts (no global atomics anywhere)
  prep_kernel<<<PB_TOT, 256, 0, stream>>>(ei32, ei64, flags, c1, s, prm, w1t, w2t, w3t);
  // 3-5) scan of c1 -> off1 (per-(bin,chunk) offsets)
  scanA_kernel<<<SBLK, 256, 0, stream>>>(c1, bsum);
  scanB_kernel<<<1, 256, 0, stream>>>(bsum, boff);
  scanC_kernel<<<SBLK, 256, 0, stream>>>(c1, boff, off1);

  const float *as1 = prm + H_POFF[1], *ad1 = prm + H_POFF[2], *b1 = prm + H_POFF[3];
  const float *as2 = prm + H_POFF[5], *ad2 = prm + H_POFF[6], *b2 = prm + H_POFF[7];
  const float *as3 = prm + H_POFF[9], *ad3 = prm + H_POFF[10], *b3 = prm + H_POFF[11];

  // 6) layer-1 GEMM(+al, direct-from-x, slab-8 h out) || coarse scatter
  gemm1_phaseC<<<GB1 + NCHK, 256, 0, stream>>>(
      d_in[0], flags, (const unsigned short*)w1t, h1s, as1, ad1, als1, ald1,
      ei32, ei64, off1, tmp);
  // 7) per-bucket fine sort -> rowptr + ssrt
  phaseD_kernel<<<NB1, 256, 0, stream>>>(off1, tmp, rowptr, ssrt);
  // 8) slab-aggregate L1 (8 slabs; slab = bid%8 -> XCD-resident)
  agg_slab<8><<<((N + 127) / 128) * 8, 256, 0, stream>>>(
      rowptr, ssrt, als1, ald1, (const unsigned short*)h1s, b1,
      (unsigned short*)hA1s);
  // 9) layer-2 GEMM(+al) from slab-8 A, slab-4 h out
  gemm_al<128, 64, 8><<<GB1, 256, 0, stream>>>(
      (const unsigned short*)hA1s, (const unsigned short*)w2t, h2s,
      as2, ad2, als2, ald2);
  // 10) slab-aggregate L2 (4 slabs; slab = bid%4)
  agg_slab<4><<<((N + 127) / 128) * 4, 256, 0, stream>>>(
      rowptr, ssrt, als2, ald2, (const unsigned short*)h2s, b2,
      (unsigned short*)hA2s);
  // 11) layer-3 GEMM(+al) from slab-4 A, h3 = [N][16]  (als ping-pong)
  gemm_al<64, 16, 4><<<GB1, 256, 0, stream>>>(
      (const unsigned short*)hA2s, (const unsigned short*)w3t, h3,
      as3, ad3, als1, ald1);
  // 12) final aggregate L3 -> d_out (h3 3.2 MB: already L2-resident/XCD)
  aggregate_csr<16, false, true><<<(N + 63) / 64, 256, 0, stream>>>(
      rowptr, ssrt, als1, ald1, (const unsigned short*)h3, b3, nullptr, d_out, flags);
}

// Round 11
// 312.021 us; speedup vs baseline: 1.7121x; 1.7121x over previous
//
#include <hip/hip_runtime.h>
#include <hip/hip_bf16.h>

typedef __hip_bfloat16 bf16;
typedef __attribute__((ext_vector_type(8))) __bf16 bf16x8;
typedef __attribute__((ext_vector_type(4))) float f32x4;

static constexpr int N = 100000;
static constexpr int E = 1600000;
static constexpr int ETOT = E + N;   // self-loops appended after the E edges
static constexpr float SLOPE = 0.2f;

// ---- param table: W1,as1,ad1,b1, W2,as2,ad2,b2, W3,as3,ad3,b3 (fp32 flat) --
__device__ __constant__ int c_poff[12] = {0, 16384, 16512, 16640,
                                          16768, 24960, 25024, 25088,
                                          25152, 26176, 26192, 26208};
static constexpr int PTOT = 26224;
static constexpr int H_POFF[12] = {0, 16384, 16512, 16640, 16768, 24960,
                                   25024, 25088, 25152, 26176, 26192, 26208};

struct Src12 { const void* p[12]; };

__device__ __forceinline__ float bfLo(unsigned u) { return __uint_as_float(u << 16); }
__device__ __forceinline__ float bfHi(unsigned u) { return __uint_as_float(u & 0xFFFF0000u); }

__device__ __forceinline__ void fma8(const uint4 r, float e, float* acc) {
  acc[0] = fmaf(e, bfLo(r.x), acc[0]);
  acc[1] = fmaf(e, bfHi(r.x), acc[1]);
  acc[2] = fmaf(e, bfLo(r.y), acc[2]);
  acc[3] = fmaf(e, bfHi(r.y), acc[3]);
  acc[4] = fmaf(e, bfLo(r.z), acc[4]);
  acc[5] = fmaf(e, bfHi(r.z), acc[5]);
  acc[6] = fmaf(e, bfLo(r.w), acc[6]);
  acc[7] = fmaf(e, bfHi(r.w), acc[7]);
}

__device__ __forceinline__ void fma4(const uint2 r, float e, float* acc) {
  acc[0] = fmaf(e, bfLo(r.x), acc[0]);
  acc[1] = fmaf(e, bfHi(r.x), acc[1]);
  acc[2] = fmaf(e, bfLo(r.y), acc[2]);
  acc[3] = fmaf(e, bfHi(r.y), acc[3]);
}

__device__ __forceinline__ float edge_ex(float l) {
  l = (l > 0.f) ? l : SLOPE * l;
  return __expf(l);
}

__device__ __forceinline__ void loadEdge(const int* __restrict__ ei32,
                                         const long long* __restrict__ ei64,
                                         int use64, int t, int& s, int& d) {
  if (t >= E) { s = d = t - E; return; }
  if (use64) { s = (int)ei64[t]; d = (int)ei64[E + t]; }
  else       { s = ei32[t];      d = ei32[E + t]; }
}

__device__ __forceinline__ unsigned pk2(float a, float b) {
  bf16 x = __float2bfloat16(a), y = __float2bfloat16(b);
  unsigned short ux = *(unsigned short*)&x, uy = *(unsigned short*)&y;
  return ((unsigned)uy << 16) | ux;
}

// ---- bucket-sort geometry ----
static constexpr int CHUNK = 8192;
static constexpr int NCHK  = (ETOT + CHUNK - 1) / CHUNK;   // 208
static constexpr int NB1   = (N + 511) / 512;              // 196 coarse buckets
static constexpr int M1    = NB1 * NCHK;                   // 40768
static constexpr int SBLK  = (M1 + 255) / 256;             // 160

// ---- flags: flags[0]=edge idx is int64; flags[1]=float tensors are fp32 ---
__global__ __launch_bounds__(256) void detect_kernel(
    const unsigned long long* __restrict__ ei64,
    const unsigned short* __restrict__ w1u16, int* __restrict__ flags) {
  const int t = threadIdx.x;
  __shared__ unsigned long long bl[4];
  __shared__ unsigned long long sb64;
  const int w = t >> 6;
  bool p64 = (t < 64) && (ei64[t] >= (unsigned long long)N);
  unsigned long long b64 = __ballot(p64);
  if (t == 0) sb64 = b64;
  // W1 glorot-bounded (|v|<=0.154) -> bf16 exp field < 126; fp32 low halves
  // are random -> exp>=126 appears within 256 samples w.h.p.
  bool pf = (((w1u16[t] >> 7) & 0xFFu) >= 126u);
  unsigned long long bf_ = __ballot(pf);
  if ((t & 63) == 0) bl[w] = bf_;
  __syncthreads();
  if (t == 0) {
    flags[0] = (sb64 == 0ull) ? 1 : 0;
    flags[1] = ((bl[0] | bl[1] | bl[2] | bl[3]) != 0ull) ? 1 : 0;
  }
}

// ---- K2: phase A (coarse LDS histogram) || param/W converts ---------------
static constexpr int PB_PAR = (PTOT + 255) / 256;  // 103
static constexpr int PB_W1  = 128 * 128 / 256;     // 64
static constexpr int PB_W2  = 128 * 64 / 256;      // 32
static constexpr int PB_W3  = 64 * 16 / 256;       // 4
static constexpr int PB_TOT = NCHK + PB_PAR + PB_W1 + PB_W2 + PB_W3;

__device__ __forceinline__ void conv_w(const void* W, int kd, int dout, int f32,
                                       bf16* __restrict__ wt, int idx) {
  int n = idx / kd, k = idx - n * kd;
  float v = f32 ? ((const float*)W)[k * dout + n]
                : __bfloat162float(((const bf16*)W)[k * dout + n]);
  wt[idx] = __float2bfloat16(v);
}

__global__ __launch_bounds__(256) void prep_kernel(
    const int* __restrict__ ei32, const long long* __restrict__ ei64,
    const int* __restrict__ flags, int* __restrict__ c1,
    Src12 s, float* __restrict__ prm,
    bf16* __restrict__ w1t, bf16* __restrict__ w2t, bf16* __restrict__ w3t) {
  const int b = blockIdx.x, tid = threadIdx.x;
  const int f64 = flags[0], f32 = flags[1];
  if (b < NCHK) {
    __shared__ int h1[NB1];
    if (tid < NB1) h1[tid] = 0;
    __syncthreads();
    const int t0 = b * CHUNK;
#pragma unroll 4
    for (int i = tid; i < CHUNK; i += 256) {
      int t = t0 + i;
      if (t < ETOT) {
        int d = (t >= E) ? (t - E) : (f64 ? (int)ei64[E + t] : ei32[E + t]);
        atomicAdd(&h1[d >> 9], 1);
      }
    }
    __syncthreads();
    if (tid < NB1) c1[tid * NCHK + b] = h1[tid];   // bin-major
  } else if (b < NCHK + PB_PAR) {
    int t = (b - NCHK) * 256 + tid;
    if (t < PTOT) {
      int k = 0;
#pragma unroll
      for (int i = 1; i < 12; ++i)
        if (t >= c_poff[i]) k = i;
      int j = t - c_poff[k];
      prm[t] = f32 ? ((const float*)s.p[k])[j]
                   : __bfloat162float(((const bf16*)s.p[k])[j]);
    }
  } else if (b < NCHK + PB_PAR + PB_W1) {
    conv_w(s.p[0], 128, 128, f32, w1t, (b - NCHK - PB_PAR) * 256 + tid);
  } else if (b < NCHK + PB_PAR + PB_W1 + PB_W2) {
    conv_w(s.p[4], 128, 64, f32, w2t, (b - NCHK - PB_PAR - PB_W1) * 256 + tid);
  } else {
    conv_w(s.p[8], 64, 16, f32, w3t, (b - NCHK - PB_PAR - PB_W1 - PB_W2) * 256 + tid);
  }
}

// ---- 3-phase exclusive scan of c1[0..M1) -> off1 --------------------------
__global__ __launch_bounds__(256) void scanA_kernel(const int* __restrict__ c1,
                                                    int* __restrict__ bsum) {
  __shared__ int red[256];
  const int t = threadIdx.x;
  const int i = blockIdx.x * 256 + t;
  red[t] = (i < M1) ? c1[i] : 0;
  __syncthreads();
#pragma unroll
  for (int off = 128; off > 0; off >>= 1) {
    if (t < off) red[t] += red[t + off];
    __syncthreads();
  }
  if (t == 0) bsum[blockIdx.x] = red[0];
}

__global__ __launch_bounds__(256) void scanB_kernel(const int* __restrict__ bsum,
                                                    int* __restrict__ boff) {
  __shared__ int s[256];
  const int t = threadIdx.x;
  const int v = (t < SBLK) ? bsum[t] : 0;
  s[t] = v;
  __syncthreads();
  for (int off = 1; off < 256; off <<= 1) {
    int u = (t >= off) ? s[t - off] : 0;
    __syncthreads();
    s[t] += u;
    __syncthreads();
  }
  if (t < SBLK) boff[t] = s[t] - v;
}

__global__ __launch_bounds__(256) void scanC_kernel(const int* __restrict__ c1,
                                                    const int* __restrict__ boff,
                                                    int* __restrict__ off1) {
  __shared__ int s[256];
  const int t = threadIdx.x;
  const int i = blockIdx.x * 256 + t;
  const int v = (i < M1) ? c1[i] : 0;
  s[t] = v;
  __syncthreads();
#pragma unroll
  for (int off = 1; off < 256; off <<= 1) {
    int u = (t >= off) ? s[t - off] : 0;
    __syncthreads();
    s[t] += u;
    __syncthreads();
  }
  if (i < M1) off1[i] = boff[blockIdx.x] + s[t] - v;
}

// ---- phase C body: scatter edges into coarse buckets via LDS cursors ------
__device__ __forceinline__ void phaseC_body(int c, const int* __restrict__ ei32,
                                            const long long* __restrict__ ei64,
                                            int f64, const int* __restrict__ off1,
                                            int2* __restrict__ tmp) {
  __shared__ int cur[NB1];
  const int tid = threadIdx.x;
  if (tid < NB1) cur[tid] = off1[tid * NCHK + c];
  __syncthreads();
  const int t0 = c * CHUNK;
#pragma unroll 4
  for (int i = tid; i < CHUNK; i += 256) {
    int t = t0 + i;
    if (t < ETOT) {
      int s, d;
      loadEdge(ei32, ei64, f64, t, s, d);
      int pos = atomicAdd(&cur[d >> 9], 1);
      tmp[pos] = make_int2(d, s);
    }
  }
}

// ---- phase D: per-bucket fine counting sort -> rowptr + ssrt --------------
__global__ __launch_bounds__(256) void phaseD_kernel(const int* __restrict__ off1,
                                                     const int2* __restrict__ tmp,
                                                     int* __restrict__ rowptr,
                                                     int* __restrict__ ssrt) {
  __shared__ int h2[512], e2[512], cur[512];
  __shared__ int ps[256];
  const int b = blockIdx.x, t = threadIdx.x;
  const int base = off1[b * NCHK];
  const int end = (b + 1 < NB1) ? off1[(b + 1) * NCHK] : ETOT;
  const int len = end - base;
  h2[2 * t] = 0; h2[2 * t + 1] = 0;
  __syncthreads();
  for (int i = t; i < len; i += 256)
    atomicAdd(&h2[tmp[base + i].x & 511], 1);
  __syncthreads();
  // exclusive scan of h2[512] via 256 pair-partials
  const int s1 = h2[2 * t], s2 = h2[2 * t + 1];
  ps[t] = s1 + s2;
  __syncthreads();
  for (int off = 1; off < 256; off <<= 1) {
    int u = (t >= off) ? ps[t - off] : 0;
    __syncthreads();
    ps[t] += u;
    __syncthreads();
  }
  const int ep = ps[t] - (s1 + s2);   // exclusive pair prefix
  e2[2 * t] = ep;
  e2[2 * t + 1] = ep + s1;
  cur[2 * t] = ep;
  cur[2 * t + 1] = ep + s1;
  __syncthreads();
  // rowptr for the 512 dst nodes of this bucket
#pragma unroll
  for (int k = 0; k < 2; ++k) {
    int f = 2 * t + k;
    int node = (b << 9) + f;
    if (node < N) rowptr[node] = base + e2[f];
  }
  if (b == 0 && t == 0) rowptr[N] = ETOT;
  // scatter src into final dst-sorted order
  for (int i = t; i < len; i += 256) {
    int2 e = tmp[base + i];
    int pos = base + atomicAdd(&cur[e.x & 511], 1);
    ssrt[pos] = e.y;
  }
}

// -------- MFMA GEMM body (64 rows x DOUT) + fused al epilogue --------------
// XD: stage A directly from x (fp32 or bf16 per flags[1]).
template <int KD, int DOUT, bool XD>
__device__ __forceinline__ void gemm_body(int bb, const void* __restrict__ inv,
                                          const int* __restrict__ flags,
                                          const unsigned short* __restrict__ wt,
                                          bf16* __restrict__ h,
                                          const float* __restrict__ a_s,
                                          const float* __restrict__ a_d,
                                          float* __restrict__ als,
                                          float* __restrict__ ald) {
  constexpr int SA = KD + 8;
  constexpr int NT = DOUT / 16;      // 8 / 4 / 1
  constexpr int KS = KD / 32;        // 4 / 4 / 2
  __shared__ unsigned short sA[64 * SA];
  __shared__ unsigned short sB[DOUT * SA];
  const int tid = threadIdx.x;
  const int m0 = bb * 64;
  for (int idx = tid; idx < DOUT * KD / 8; idx += 256) {
    int n = idx / (KD / 8), k8 = idx - n * (KD / 8);
    *(uint4*)(sB + n * SA + k8 * 8) = *(const uint4*)(wt + n * KD + k8 * 8);
  }
  const bool f32 = XD ? (flags[1] != 0) : false;
  for (int idx = tid; idx < 64 * KD / 8; idx += 256) {
    int r = idx / (KD / 8), k8 = idx - r * (KD / 8);
    int m = m0 + r;
    uint4 v = make_uint4(0, 0, 0, 0);
    if (m < N) {
      if (XD && f32) {
        const float4 v0 = *((const float4*)inv + ((size_t)m * KD + k8 * 8) / 4);
        const float4 v1 = *((const float4*)inv + ((size_t)m * KD + k8 * 8) / 4 + 1);
        v = make_uint4(pk2(v0.x, v0.y), pk2(v0.z, v0.w),
                       pk2(v1.x, v1.y), pk2(v1.z, v1.w));
      } else {
        v = *((const uint4*)inv + ((size_t)m * KD + k8 * 8) / 8);
      }
    }
    *(uint4*)(sA + r * SA + k8 * 8) = v;
  }
  __syncthreads();
  const int lane = tid & 63;
  const int wv = tid >> 6;
  const int lr = lane & 15;
  const int q = lane >> 4;
  f32x4 acc[NT];
#pragma unroll
  for (int t = 0; t < NT; ++t)
#pragma unroll
    for (int r = 0; r < 4; ++r) acc[t][r] = 0.f;
  const int arow = wv * 16 + lr;
#pragma unroll
  for (int ks = 0; ks < KS; ++ks) {
    const int k0 = ks * 32 + q * 8;
    const bf16x8 a = *(const bf16x8*)(sA + arow * SA + k0);
#pragma unroll
    for (int t = 0; t < NT; ++t) {
      const bf16x8 b = *(const bf16x8*)(sB + (t * 16 + lr) * SA + k0);
      acc[t] = __builtin_amdgcn_mfma_f32_16x16x32_bf16(a, b, acc[t], 0, 0, 0);
    }
  }
  // al epilogue: row-dots with a_s/a_d, reduce over 16 col-lanes
  float ps[4] = {0.f, 0.f, 0.f, 0.f}, pd[4] = {0.f, 0.f, 0.f, 0.f};
#pragma unroll
  for (int t = 0; t < NT; ++t) {
    const float av = a_s[t * 16 + lr];
    const float dv = a_d[t * 16 + lr];
#pragma unroll
    for (int r = 0; r < 4; ++r) {
      ps[r] = fmaf(acc[t][r], av, ps[r]);
      pd[r] = fmaf(acc[t][r], dv, pd[r]);
    }
  }
#pragma unroll
  for (int m = 1; m < 16; m <<= 1)
#pragma unroll
    for (int r = 0; r < 4; ++r) {
      ps[r] += __shfl_xor(ps[r], m, 64);
      pd[r] += __shfl_xor(pd[r], m, 64);
    }
  const int mb = m0 + wv * 16 + q * 4;
  if (lr == 0) {
#pragma unroll
    for (int r = 0; r < 4; ++r) {
      int m = mb + r;
      if (m < N) { als[m] = ps[r]; ald[m] = pd[r]; }
    }
  }
#pragma unroll
  for (int t = 0; t < NT; ++t)
#pragma unroll
    for (int r = 0; r < 4; ++r) {
      int m = mb + r;
      if (m < N) h[(size_t)m * DOUT + t * 16 + lr] = __float2bfloat16(acc[t][r]);
    }
}

// layer-1 GEMM (direct from x) fused with bucket phase C (independent tasks)
static constexpr int GB1 = (N + 63) / 64;  // 1563

__global__ __launch_bounds__(256) void gemm1_phaseC(
    const void* __restrict__ x, const int* __restrict__ flags,
    const unsigned short* __restrict__ wt, bf16* __restrict__ h,
    const float* __restrict__ a_s, const float* __restrict__ a_d,
    float* __restrict__ als, float* __restrict__ ald,
    const int* __restrict__ ei32, const long long* __restrict__ ei64,
    const int* __restrict__ off1, int2* __restrict__ tmp) {
  if (blockIdx.x < GB1) {
    gemm_body<128, 128, true>(blockIdx.x, x, flags, wt, h, a_s, a_d, als, ald);
  } else {
    int c = blockIdx.x - GB1;
    if (c < NCHK) phaseC_body(c, ei32, ei64, flags[0], off1, tmp);
  }
}

// ---- fused aggregate(layer l) + GEMM(layer l+1) ---------------------------
// Block owns BR consecutive dst nodes == one GEMM A-tile (BR/16 waves run
// the MFMA). Round-4/6 counters: gather BW linear in occupancy; cap is grid
// quantization + drain tail. BR=16 for the L1 kernel -> 6250 blocks =
// 24.4/CU -> 3 refill generations, quarter-size tail (round-6's BR=32 gave
// 12.2/CU, occ 64%, 72us). L2 kernel needs BR=32 (TPN=8 -> NPB=32 rows min).
// x4 unroll only (x8 spilled, round 5); B from global (L2-resident w2t/w3t);
// launch_bounds(256,8).
template <int KD, int DOUT, int BR>
__global__ __launch_bounds__(256, 8) void agg_gemm(
    const int* __restrict__ rowptr, const int* __restrict__ ssrt,
    const float* __restrict__ als_in, const float* __restrict__ ald_in,
    const unsigned short* __restrict__ hb, const float* __restrict__ bias_in,
    const unsigned short* __restrict__ wt, bf16* __restrict__ hout,
    const float* __restrict__ a_s, const float* __restrict__ a_d,
    float* __restrict__ als_out, float* __restrict__ ald_out) {
  constexpr int SA = KD + 8;
  constexpr int NT = DOUT / 16;      // 4 / 1
  constexpr int KS = KD / 32;        // 4 / 2
  constexpr int TPN = KD / 8;        // agg threads per node: 16 / 8
  constexpr int NPB = 256 / TPN;     // nodes per batch: 16 / 32
  constexpr int NBAT = BR / NPB;     // 1 / 1
  constexpr int NWV = BR / 16;       // MFMA waves: 1 / 2
  static_assert(BR >= NPB && NBAT * NPB == BR, "geometry");
  __shared__ unsigned short sA[BR * SA];
  const int tid = threadIdx.x;
  const int m0 = blockIdx.x * BR;
  const int sub = tid % TPN;
  const int rb = tid / TPN;
  const int col0 = sub * 8;
#pragma unroll
  for (int bat = 0; bat < NBAT; ++bat) {
    const int r = bat * NPB + rb;
    const int d = m0 + r;
    uint4 w = make_uint4(0, 0, 0, 0);
    if (d < N) {
      const int p0 = rowptr[d], p1 = rowptr[d + 1];
      const float ad = ald_in[d];
      float acc[8];
#pragma unroll
      for (int c = 0; c < 8; ++c) acc[c] = 0.f;
      float sum = 0.f;
      int p = p0;
      for (; p + 4 <= p1; p += 4) {
        const int s0 = ssrt[p + 0];
        const int s1 = ssrt[p + 1];
        const int s2 = ssrt[p + 2];
        const int s3 = ssrt[p + 3];
        const uint4 r0 = *reinterpret_cast<const uint4*>(hb + (size_t)s0 * KD + col0);
        const uint4 r1 = *reinterpret_cast<const uint4*>(hb + (size_t)s1 * KD + col0);
        const uint4 r2 = *reinterpret_cast<const uint4*>(hb + (size_t)s2 * KD + col0);
        const uint4 r3 = *reinterpret_cast<const uint4*>(hb + (size_t)s3 * KD + col0);
        const float x0 = edge_ex(als_in[s0] + ad);
        const float x1 = edge_ex(als_in[s1] + ad);
        const float x2 = edge_ex(als_in[s2] + ad);
        const float x3 = edge_ex(als_in[s3] + ad);
        sum += (x0 + x1) + (x2 + x3);
        fma8(r0, x0, acc);
        fma8(r1, x1, acc);
        fma8(r2, x2, acc);
        fma8(r3, x3, acc);
      }
      for (; p < p1; ++p) {
        const int s = ssrt[p];
        const uint4 rr = *reinterpret_cast<const uint4*>(hb + (size_t)s * KD + col0);
        const float x = edge_ex(als_in[s] + ad);
        sum += x;
        fma8(rr, x, acc);
      }
      const float inv = 1.f / sum;
      float v[8];
#pragma unroll
      for (int c = 0; c < 8; ++c) {
        float t = acc[c] * inv + bias_in[col0 + c];
        v[c] = (t > 0.f) ? t : 0.f;   // ReLU between layers
      }
      w = make_uint4(pk2(v[0], v[1]), pk2(v[2], v[3]),
                     pk2(v[4], v[5]), pk2(v[6], v[7]));
    }
    *(uint4*)(sA + r * SA + col0) = w;
  }
  __syncthreads();
  // ---- MFMA tile + al epilogue (waves 0..NWV-1); B from global (L2) ----
  const int lane = tid & 63;
  const int wv = tid >> 6;
  if (wv >= NWV) return;             // wave-uniform exit, after the barrier
  const int lr = lane & 15;
  const int q = lane >> 4;
  f32x4 acc[NT];
#pragma unroll
  for (int t = 0; t < NT; ++t)
#pragma unroll
    for (int r = 0; r < 4; ++r) acc[t][r] = 0.f;
  const int arow = wv * 16 + lr;
#pragma unroll
  for (int ks = 0; ks < KS; ++ks) {
    const int k0 = ks * 32 + q * 8;
    const bf16x8 a = *(const bf16x8*)(sA + arow * SA + k0);
#pragma unroll
    for (int t = 0; t < NT; ++t) {
      const bf16x8 b = *(const bf16x8*)(wt + (t * 16 + lr) * KD + k0);
      acc[t] = __builtin_amdgcn_mfma_f32_16x16x32_bf16(a, b, acc[t], 0, 0, 0);
    }
  }
  float ps[4] = {0.f, 0.f, 0.f, 0.f}, pd[4] = {0.f, 0.f, 0.f, 0.f};
#pragma unroll
  for (int t = 0; t < NT; ++t) {
    const float av = a_s[t * 16 + lr];
    const float dv = a_d[t * 16 + lr];
#pragma unroll
    for (int r = 0; r < 4; ++r) {
      ps[r] = fmaf(acc[t][r], av, ps[r]);
      pd[r] = fmaf(acc[t][r], dv, pd[r]);
    }
  }
#pragma unroll
  for (int m = 1; m < 16; m <<= 1)
#pragma unroll
    for (int r = 0; r < 4; ++r) {
      ps[r] += __shfl_xor(ps[r], m, 64);
      pd[r] += __shfl_xor(pd[r], m, 64);
    }
  const int mb = m0 + wv * 16 + q * 4;
  if (lr == 0) {
#pragma unroll
    for (int r = 0; r < 4; ++r) {
      int m = mb + r;
      if (m < N) { als_out[m] = ps[r]; ald_out[m] = pd[r]; }
    }
  }
#pragma unroll
  for (int t = 0; t < NT; ++t)
#pragma unroll
    for (int r = 0; r < 4; ++r) {
      int m = mb + r;
      if (m < N) hout[(size_t)m * DOUT + t * 16 + lr] = __float2bfloat16(acc[t][r]);
    }
}

// ---- final aggregate (V cols per thread; V=4 for DOUT=16 -> 1563 blocks) --
template <int DOUT, bool RELU, bool FINAL>
__global__ __launch_bounds__(256) void aggregate_csr(const int* __restrict__ rowptr,
                                                     const int* __restrict__ ssrt,
                                                     const float* __restrict__ als,
                                                     const float* __restrict__ ald,
                                                     const unsigned short* __restrict__ hb,
                                                     const float* __restrict__ bias,
                                                     bf16* __restrict__ outb,
                                                     void* __restrict__ outv,
                                                     const int* __restrict__ flags) {
  constexpr int V = (DOUT >= 64) ? 8 : 4;
  constexpr int TPN = DOUT / V;
  constexpr int NPB = 256 / TPN;
  const int sub = threadIdx.x % TPN;
  const int d = blockIdx.x * NPB + threadIdx.x / TPN;
  if (d >= N) return;
  const int p0 = rowptr[d], p1 = rowptr[d + 1];
  const float ad = ald[d];
  const int col0 = sub * V;
  float acc[V];
#pragma unroll
  for (int c = 0; c < V; ++c) acc[c] = 0.f;
  float sum = 0.f;
  int p = p0;
  for (; p + 4 <= p1; p += 4) {
    const int s0 = ssrt[p + 0];
    const int s1 = ssrt[p + 1];
    const int s2 = ssrt[p + 2];
    const int s3 = ssrt[p + 3];
    const float x0 = edge_ex(als[s0] + ad);
    const float x1 = edge_ex(als[s1] + ad);
    const float x2 = edge_ex(als[s2] + ad);
    const float x3 = edge_ex(als[s3] + ad);
    sum += (x0 + x1) + (x2 + x3);
    if constexpr (V == 8) {
      const uint4 r0 = *reinterpret_cast<const uint4*>(hb + (size_t)s0 * DOUT + col0);
      const uint4 r1 = *reinterpret_cast<const uint4*>(hb + (size_t)s1 * DOUT + col0);
      const uint4 r2 = *reinterpret_cast<const uint4*>(hb + (size_t)s2 * DOUT + col0);
      const uint4 r3 = *reinterpret_cast<const uint4*>(hb + (size_t)s3 * DOUT + col0);
      fma8(r0, x0, acc);
      fma8(r1, x1, acc);
      fma8(r2, x2, acc);
      fma8(r3, x3, acc);
    } else {
      const uint2 r0 = *reinterpret_cast<const uint2*>(hb + (size_t)s0 * DOUT + col0);
      const uint2 r1 = *reinterpret_cast<const uint2*>(hb + (size_t)s1 * DOUT + col0);
      const uint2 r2 = *reinterpret_cast<const uint2*>(hb + (size_t)s2 * DOUT + col0);
      const uint2 r3 = *reinterpret_cast<const uint2*>(hb + (size_t)s3 * DOUT + col0);
      fma4(r0, x0, acc);
      fma4(r1, x1, acc);
      fma4(r2, x2, acc);
      fma4(r3, x3, acc);
    }
  }
  for (; p < p1; ++p) {
    const int s = ssrt[p];
    const float x = edge_ex(als[s] + ad);
    sum += x;
    if constexpr (V == 8) {
      const uint4 r = *reinterpret_cast<const uint4*>(hb + (size_t)s * DOUT + col0);
      fma8(r, x, acc);
    } else {
      const uint2 r = *reinterpret_cast<const uint2*>(hb + (size_t)s * DOUT + col0);
      fma4(r, x, acc);
    }
  }
  const float inv = 1.f / sum;
  if (FINAL) {
    const bool f32o = flags[1] != 0;
#pragma unroll
    for (int c = 0; c < V; ++c) {
      float v = acc[c] * inv + bias[col0 + c];
      if (f32o) ((float*)outv)[(size_t)d * DOUT + col0 + c] = v;
      else      ((bf16*)outv)[(size_t)d * DOUT + col0 + c] = __float2bfloat16(v);
    }
  } else {
#pragma unroll
    for (int c = 0; c < V; ++c) {
      float v = acc[c] * inv + bias[col0 + c];
      if (RELU) v = (v > 0.f) ? v : 0.f;
      outb[(size_t)d * DOUT + col0 + c] = __float2bfloat16(v);
    }
  }
}

static inline size_t rup(size_t v) { return (v + 255) & ~(size_t)255; }

extern "C" void kernel_launch(void* const* d_in, const int* in_sizes, int n_in,
                              void* d_out, int out_size, void* d_ws, size_t ws_size,
                              hipStream_t stream) {
  const int* ei32 = (const int*)d_in[1];
  const long long* ei64 = (const long long*)d_in[1];

  char* p = (char*)d_ws;
  int*   flags  = (int*)p;   p += 256;
  float* prm    = (float*)p; p += rup((size_t)PTOT * 4);
  bf16*  w1t    = (bf16*)p;  p += rup((size_t)128 * 128 * 2);
  bf16*  w2t    = (bf16*)p;  p += rup((size_t)128 * 64 * 2);
  bf16*  w3t    = (bf16*)p;  p += rup((size_t)64 * 16 * 2);
  float* als1   = (float*)p; p += rup((size_t)N * 4);
  float* ald1   = (float*)p; p += rup((size_t)N * 4);
  float* als2   = (float*)p; p += rup((size_t)N * 4);
  float* ald2   = (float*)p; p += rup((size_t)N * 4);
  int*   rowptr = (int*)p;   p += rup((size_t)(N + 1) * 4);
  int*   c1     = (int*)p;   p += rup((size_t)M1 * 4);
  int*   off1   = (int*)p;   p += rup((size_t)M1 * 4);
  int*   bsum   = (int*)p;   p += rup((size_t)SBLK * 4);
  int*   boff   = (int*)p;   p += rup((size_t)SBLK * 4);
  int2*  tmp    = (int2*)p;  p += rup((size_t)ETOT * 8);
  int*   ssrt   = (int*)p;   p += rup((size_t)ETOT * 4);
  bf16*  h1     = (bf16*)p;  p += rup((size_t)N * 128 * 2);
  bf16*  h2     = (bf16*)p;  p += rup((size_t)N * 64 * 2);
  bf16*  h3     = (bf16*)p;  // + 3.2 MB -> total ~64 MB (ws proven >= 99 MB)

  Src12 s;
  for (int i = 0; i < 12; ++i) s.p[i] = d_in[2 + i];

  // 1) flags (parallel ballots, 1 block)
  detect_kernel<<<1, 256, 0, stream>>>(
      (const unsigned long long*)d_in[1], (const unsigned short*)d_in[2], flags);
  // 2) coarse LDS histograms || param/W converts (no global atomics anywhere)
  prep_kernel<<<PB_TOT, 256, 0, stream>>>(ei32, ei64, flags, c1, s, prm, w1t, w2t, w3t);
  // 3-5) scan of c1 -> off1 (per-(bin,chunk) offsets)
  scanA_kernel<<<SBLK, 256, 0, stream>>>(c1, bsum);
  scanB_kernel<<<1, 256, 0, stream>>>(bsum, boff);
  scanC_kernel<<<SBLK, 256, 0, stream>>>(c1, boff, off1);

  const float *as1 = prm + H_POFF[1], *ad1 = prm + H_POFF[2], *b1 = prm + H_POFF[3];
  const float *as2 = prm + H_POFF[5], *ad2 = prm + H_POFF[6], *b2 = prm + H_POFF[7];
  const float *as3 = prm + H_POFF[9], *ad3 = prm + H_POFF[10], *b3 = prm + H_POFF[11];

  // 6) layer-1 GEMM(+al, direct-from-x) || coarse scatter into buckets
  gemm1_phaseC<<<GB1 + NCHK, 256, 0, stream>>>(
      d_in[0], flags, (const unsigned short*)w1t, h1, as1, ad1, als1, ald1,
      ei32, ei64, off1, tmp);
  // 7) per-bucket fine sort -> rowptr + ssrt
  phaseD_kernel<<<NB1, 256, 0, stream>>>(off1, tmp, rowptr, ssrt);
  // 8) fused: aggregate L1 + layer-2 GEMM(+al); BR=16 -> 6250 blocks
  agg_gemm<128, 64, 16><<<(N + 15) / 16, 256, 0, stream>>>(
      rowptr, ssrt, als1, ald1, (const unsigned short*)h1, b1,
      (const unsigned short*)w2t, h2, as2, ad2, als2, ald2);
  // 9) fused: aggregate L2 + layer-3 GEMM(+al); BR=32 (TPN=8 needs 32 rows)
  agg_gemm<64, 16, 32><<<(N + 31) / 32, 256, 0, stream>>>(
      rowptr, ssrt, als2, ald2, (const unsigned short*)h2, b2,
      (const unsigned short*)w3t, h3, as3, ad3, als1, ald1);
  // 10) final aggregate L3 -> d_out (dtype per flags[1]); V=4 -> 1563 blocks
  aggregate_csr<16, false, true><<<(N + 63) / 64, 256, 0, stream>>>(
      rowptr, ssrt, als1, ald1, (const unsigned short*)h3, b3, nullptr, d_out, flags);
}